// Round 2
// 576.790 us; speedup vs baseline: 1.0158x; 1.0158x over previous
//
#include <hip/hip_runtime.h>

// Shapes fixed by the reference setup.
#define BB 32
#define HH 16
#define NN 1024
#define DD 128

// Native clang vector type — __builtin_nontemporal_store rejects HIP's float4 class.
typedef float fvec4 __attribute__((ext_vector_type(4)));

// One block per (b,h) row: 1024 threads = 16 waves = 32 half-waves.
//   Phase A: padd[b] = first index with padding==0 (else N), block-min reduce.
//   Phase B: score[n] = dot(t[bh,n,:], w2)  (half-wave per row, shuffle reduce).
//            w1/s and concat_b cancel under softmax (shift invariance).
//   Phase C: masked softmax over the 1024 scores in LDS -> factor[n] = 1+attn[n].
//   Phase D: out = t * factor, re-reading the row while it is still L2/L3-hot;
//            nontemporal stores keep the out-stream from evicting t.
__global__ __launch_bounds__(1024) void fused_kernel(const float* __restrict__ t,
                                                     const int* __restrict__ padding,
                                                     const float* __restrict__ w2,
                                                     float* __restrict__ out) {
    const int bh   = blockIdx.x;        // 0..B*H-1
    const int b    = bh >> 4;           // H = 16
    const int tid  = threadIdx.x;       // 0..1023
    const int wid  = tid >> 6;          // wave 0..15
    const int lane = tid & 63;

    __shared__ float s_fac[NN];         // scores, then factors
    __shared__ int   red_i[16];
    __shared__ float red_f[16];

    const float* trow = t + (long)bh * NN * DD;

    // ---- Phase A: per-wave part of padd reduction (one int per thread) ----
    int lm = (padding[b * NN + tid] == 0) ? tid : NN;
#pragma unroll
    for (int off = 32; off; off >>= 1) lm = min(lm, __shfl_xor(lm, off));
    if (lane == 0) red_i[wid] = lm;

    // ---- Phase B: scores. Half-wave (32 lanes) per row, 32 rows per half-wave.
    const int hw = tid >> 5;            // 0..31
    const int l  = tid & 31;
    const float4 wv = ((const float4*)w2)[l];
#pragma unroll 4
    for (int it = 0; it < 32; ++it) {
        const int n = hw * 32 + it;
        const float4 tv = ((const float4*)(trow + (long)n * DD))[l];
        float p = tv.x * wv.x + tv.y * wv.y + tv.z * wv.z + tv.w * wv.w;
        p += __shfl_xor(p, 1);
        p += __shfl_xor(p, 2);
        p += __shfl_xor(p, 4);
        p += __shfl_xor(p, 8);
        p += __shfl_xor(p, 16);
        if (l == 0) s_fac[n] = p;
    }
    __syncthreads();                    // covers red_i and s_fac writes

    int padd = NN;
#pragma unroll
    for (int k = 0; k < 16; ++k) padd = min(padd, red_i[k]);

    // ---- Phase C: masked softmax over s_fac, one score per thread ----
    const float sc  = s_fac[tid];
    const float NEG = -3.4e38f;
    float m = (tid < padd) ? sc : NEG;
#pragma unroll
    for (int off = 32; off; off >>= 1) m = fmaxf(m, __shfl_xor(m, off));
    if (lane == 0) red_f[wid] = m;
    __syncthreads();
    float M = NEG;
#pragma unroll
    for (int k = 0; k < 16; ++k) M = fmaxf(M, red_f[k]);
    __syncthreads();                    // before red_f reuse

    const float e = (tid < padd) ? __expf(sc - M) : 0.f;
    float s = e;
#pragma unroll
    for (int off = 32; off; off >>= 1) s += __shfl_xor(s, off);
    if (lane == 0) red_f[wid] = s;
    __syncthreads();
    float S = 0.f;
#pragma unroll
    for (int k = 0; k < 16; ++k) S += red_f[k];

    const float inv = (S > 0.f) ? (1.0f / S) : 0.f;   // padd==0 never occurs here
    s_fac[tid] = 1.f + e * inv;         // masked n -> exactly 1
    __syncthreads();

    // ---- Phase D: out = t * factor. Row is L2/L3-hot from Phase B. ----
    const float4* t4 = (const float4*)trow;
    fvec4*        o4 = (fvec4*)(out + (long)bh * NN * DD);
#pragma unroll 4
    for (int it = 0; it < 32; ++it) {
        const int i4 = it * 1024 + tid;           // float4 index in row
        const float f = s_fac[i4 >> 5];           // 32 float4 per D=128 row (broadcast)
        float4 v = t4[i4];
        fvec4 nv = {v.x * f, v.y * f, v.z * f, v.w * f};
        __builtin_nontemporal_store(nv, o4 + i4); // don't evict t from L2/L3
    }
}

extern "C" void kernel_launch(void* const* d_in, const int* in_sizes, int n_in,
                              void* d_out, int out_size, void* d_ws, size_t ws_size,
                              hipStream_t stream) {
    // inputs: 0 t_1 (unused — softmax shift-invariance), 1 t, 2 padding, 3 N,
    //         4 concat_w (w1 unused | w2), 5 concat_b (unused — cancels)
    const float* t       = (const float*)d_in[1];
    const int*   padding = (const int*)d_in[2];
    const float* cw      = (const float*)d_in[4];
    float*       out     = (float*)d_out;

    fused_kernel<<<BB * HH, 1024, 0, stream>>>(t, padding, cw + DD, out);
}

// Round 3
// 574.329 us; speedup vs baseline: 1.0201x; 1.0043x over previous
//
#include <hip/hip_runtime.h>

// Shapes fixed by the reference setup.
#define BB 32
#define HH 16
#define NN 1024
#define DD 128

// Native clang vector type — __builtin_nontemporal_store rejects HIP's float4 class.
typedef float fvec4 __attribute__((ext_vector_type(4)));

// One block per (b,h) row: 1024 threads = 16 waves = 32 half-waves.
//   Phase A: padd[b] = first index with padding==0 (else N), block-min reduce.
//   Phase B: score[n] = dot(t[bh,n,:], w2). Half-wave per row-group, 4-deep
//            double-buffered loads (MLP!) + pair-merged butterfly reduce.
//   Phase C: masked softmax over the 1024 scores in LDS -> factor[n] = 1+attn[n].
//   Phase D: out = t * factor; re-read is L2/L3-hot; NT stores for out.
__global__ __launch_bounds__(1024) void fused_kernel(const float* __restrict__ t,
                                                     const int* __restrict__ padding,
                                                     const float* __restrict__ w2,
                                                     float* __restrict__ out) {
    const int bh   = blockIdx.x;        // 0..B*H-1
    const int b    = bh >> 4;           // H = 16
    const int tid  = threadIdx.x;       // 0..1023
    const int wid  = tid >> 6;          // wave 0..15
    const int lane = tid & 63;

    __shared__ float s_fac[NN];         // scores, then factors
    __shared__ int   red_i[16];
    __shared__ float red_f[16];

    const float* trow = t + (long)bh * NN * DD;

    // ---- Phase A: per-wave part of padd reduction (one int per thread) ----
    int lm = (padding[b * NN + tid] == 0) ? tid : NN;
#pragma unroll
    for (int off = 32; off; off >>= 1) lm = min(lm, __shfl_xor(lm, off));
    if (lane == 0) red_i[wid] = lm;

    // ---- Phase B: scores. Half-wave (32 lanes) owns 32 consecutive rows. ----
    const int hw = tid >> 5;            // 0..31
    const int l  = tid & 31;
    const float4 wv = ((const float4*)w2)[l];
    const float4* rowp = (const float4*)(trow + (long)(hw * 32) * DD); // + r*32 + l

    float4 cur[4], nxt[4];
#pragma unroll
    for (int j = 0; j < 4; ++j) cur[j] = rowp[j * 32 + l];

#pragma unroll
    for (int g = 0; g < 8; ++g) {
        if (g < 7) {
#pragma unroll
            for (int j = 0; j < 4; ++j) nxt[j] = rowp[(g + 1) * 128 + j * 32 + l];
        }
        float p[4];
#pragma unroll
        for (int j = 0; j < 4; ++j)
            p[j] = cur[j].x * wv.x + cur[j].y * wv.y + cur[j].z * wv.z + cur[j].w * wv.w;

        // Pair-merged butterfly: 5 shuffles reduce TWO rows at once.
        // After merge, lanes l<16 carry row (2*pr), lanes l>=16 carry row (2*pr+1).
#pragma unroll
        for (int pr = 0; pr < 2; ++pr) {
            const float a = p[2 * pr], bq = p[2 * pr + 1];
            float x = (l < 16) ? a : bq;
            float y = (l < 16) ? bq : a;
            x += __shfl_xor(y, 16);
            x += __shfl_xor(x, 8);
            x += __shfl_xor(x, 4);
            x += __shfl_xor(x, 2);
            x += __shfl_xor(x, 1);
            const int n = hw * 32 + g * 4 + 2 * pr;
            if (l == 0)  s_fac[n]     = x;
            if (l == 16) s_fac[n + 1] = x;
        }
        if (g < 7) {
#pragma unroll
            for (int j = 0; j < 4; ++j) cur[j] = nxt[j];
        }
    }
    __syncthreads();                    // covers red_i and s_fac writes

    int padd = NN;
#pragma unroll
    for (int k = 0; k < 16; ++k) padd = min(padd, red_i[k]);

    // ---- Phase C: masked softmax over s_fac, one score per thread ----
    const float sc  = s_fac[tid];
    const float NEG = -3.4e38f;
    float m = (tid < padd) ? sc : NEG;
#pragma unroll
    for (int off = 32; off; off >>= 1) m = fmaxf(m, __shfl_xor(m, off));
    if (lane == 0) red_f[wid] = m;
    __syncthreads();
    float M = NEG;
#pragma unroll
    for (int k = 0; k < 16; ++k) M = fmaxf(M, red_f[k]);
    __syncthreads();                    // before red_f reuse

    const float e = (tid < padd) ? __expf(sc - M) : 0.f;
    float s = e;
#pragma unroll
    for (int off = 32; off; off >>= 1) s += __shfl_xor(s, off);
    if (lane == 0) red_f[wid] = s;
    __syncthreads();
    float S = 0.f;
#pragma unroll
    for (int k = 0; k < 16; ++k) S += red_f[k];

    const float inv = (S > 0.f) ? (1.0f / S) : 0.f;   // padd==0 never occurs here
    s_fac[tid] = 1.f + e * inv;         // masked n -> exactly 1
    __syncthreads();

    // ---- Phase D: out = t * factor. Row is L2/L3-hot from Phase B. ----
    const float4* t4 = (const float4*)trow;
    fvec4*        o4 = (fvec4*)(out + (long)bh * NN * DD);
#pragma unroll 8
    for (int it = 0; it < 32; ++it) {
        const int i4 = it * 1024 + tid;           // float4 index in row
        const float f = s_fac[i4 >> 5];           // broadcast within 32-lane group
        float4 v = t4[i4];
        fvec4 nv = {v.x * f, v.y * f, v.z * f, v.w * f};
        __builtin_nontemporal_store(nv, o4 + i4); // don't evict t from L2/L3
    }
}

extern "C" void kernel_launch(void* const* d_in, const int* in_sizes, int n_in,
                              void* d_out, int out_size, void* d_ws, size_t ws_size,
                              hipStream_t stream) {
    // inputs: 0 t_1 (unused — softmax shift-invariance), 1 t, 2 padding, 3 N,
    //         4 concat_w (w1 unused | w2), 5 concat_b (unused — cancels)
    const float* t       = (const float*)d_in[1];
    const int*   padding = (const int*)d_in[2];
    const float* cw      = (const float*)d_in[4];
    float*       out     = (float*)d_out;

    fused_kernel<<<BB * HH, 1024, 0, stream>>>(t, padding, cw + DD, out);
}